// Round 20
// baseline (191.302 us; speedup 1.0000x reference)
//
#include <hip/hip_runtime.h>
#include <hip/hip_bf16.h>
#include <cstdint>

typedef unsigned short u16;
typedef __bf16 bf16x8 __attribute__((ext_vector_type(8)));
typedef float f32x4 __attribute__((ext_vector_type(4)));
typedef unsigned short u16x4 __attribute__((ext_vector_type(4)));
typedef unsigned short u16x8 __attribute__((ext_vector_type(8)));
typedef unsigned uint2v __attribute__((ext_vector_type(2)));

#define B_ 2
#define T_ 2048
#define C_ 2048
#define NH_ 16
#define NKV_ 4
#define HD_ 128
// (1/sqrt(128)) * log2(e) — folded into Q
#define K2_ 0.12752004650581538f

__device__ __forceinline__ u16 f2bf(float f) {
    unsigned u = __builtin_bit_cast(unsigned, f);
    unsigned r = u + 0x7FFFu + ((u >> 16) & 1u);
    return (u16)(r >> 16);
}

__device__ __forceinline__ float bf2f(u16 v) {
    unsigned u = ((unsigned)v) << 16;
    return __builtin_bit_cast(float, u);
}

__device__ __forceinline__ unsigned cvtpk(float a, float b) {
    unsigned r;
    asm("v_cvt_pk_bf16_f32 %0, %1, %2" : "=v"(r) : "v"(a), "v"(b));
    return r;
}

__device__ __forceinline__ void gl16(const void* g, void* l) {
    auto gp = reinterpret_cast<const __attribute__((address_space(1))) unsigned*>(
        reinterpret_cast<uintptr_t>(g));
    auto lp = reinterpret_cast<__attribute__((address_space(3))) unsigned*>(
        reinterpret_cast<uintptr_t>(l));
    __builtin_amdgcn_global_load_lds(gp, lp, 16, 0, 0);
}

// ---------- fused prepass: 4 weight transposes + x convert, one launch ----------
__global__ __launch_bounds__(256) void prepass(const float* __restrict__ wq,
                                               const float* __restrict__ wk,
                                               const float* __restrict__ wv,
                                               const float* __restrict__ wo,
                                               const float4* __restrict__ x,
                                               u16* __restrict__ wqkvT,
                                               u16* __restrict__ woT,
                                               u16* __restrict__ xb) {
    int bz = blockIdx.x;
    int t = threadIdx.x;
    if (bz >= 10240) {  // convert x
        int i = (bz - 10240) * 256 + t;
        float4 v = x[i];
        u16x4 o;
        o[0] = f2bf(v.x); o[1] = f2bf(v.y); o[2] = f2bf(v.z); o[3] = f2bf(v.w);
        ((u16x4*)xb)[i] = o;
        return;
    }
    __shared__ float tile[32][33];
    const float* in;
    u16* out;
    int N, bx, by;
    if (bz < 4096)      { in = wq; out = wqkvT;                      N = 2048; bx = bz & 63; by = bz >> 6; }
    else if (bz < 5120) { int z = bz - 4096; in = wk; out = wqkvT + (size_t)2048 * 2048; N = 512; bx = z & 15; by = z >> 4; }
    else if (bz < 6144) { int z = bz - 5120; in = wv; out = wqkvT + (size_t)2560 * 2048; N = 512; bx = z & 15; by = z >> 4; }
    else                { int z = bz - 6144; in = wo; out = woT;     N = 2048; bx = z & 63; by = z >> 6; }
    int n0 = bx * 32, k0 = by * 32;
    int tx = t & 31, ty = t >> 5;  // 32 x 8
#pragma unroll
    for (int i = 0; i < 4; ++i)
        tile[ty * 4 + i][tx] = in[(size_t)(k0 + ty * 4 + i) * N + n0 + tx];
    __syncthreads();
#pragma unroll
    for (int i = 0; i < 4; ++i)
        out[(size_t)(n0 + ty * 4 + i) * 2048 + k0 + tx] = f2bf(tile[tx][ty * 4 + i]);
}

// ---------- GEMM (f32 out, 128^2 2-phase): used for gemm2 ----------
__global__ __launch_bounds__(256, 2) void gemm_bf16(const u16* __restrict__ A,
                                                    const u16* __restrict__ BT,
                                                    float* __restrict__ C, int N, int K) {
    __shared__ __align__(16) u16 As[2][128 * 64];
    __shared__ __align__(16) u16 Bs[2][128 * 64];
    int nwg = gridDim.x * gridDim.y;
    int bid = blockIdx.y * gridDim.x + blockIdx.x;
    int nb = (bid & 7) * (nwg >> 3) + (bid >> 3);
    int bx = nb % gridDim.x, by = nb / gridDim.x;

    int t = threadIdx.x;
    int w = t >> 6, l = t & 63;
    int wr = w >> 1, wc = w & 1;
    int lg = l >> 4, lr = l & 15;
    int m0 = by * 128, n0 = bx * 128;
    f32x4 acc[4][4] = {};

    size_t goff[4];
#pragma unroll
    for (int i = 0; i < 4; ++i) {
        int g = t + i * 256;
        goff[i] = (size_t)(g >> 3) * K * 2 + (size_t)(((g & 7) ^ ((g >> 3) & 7)) * 16);
    }
    const char* Ab = (const char*)A + (size_t)m0 * K * 2;
    const char* Bb = (const char*)BT + (size_t)n0 * K * 2;

    auto stage = [&](int kt, int buf) {
        char* Ad = (char*)As[buf] + t * 16;
        char* Bd = (char*)Bs[buf] + t * 16;
#pragma unroll
        for (int i = 0; i < 4; ++i) {
            gl16(Ab + (size_t)kt * 2 + goff[i], Ad + i * 4096);
            gl16(Bb + (size_t)kt * 2 + goff[i], Bd + i * 4096);
        }
    };

    stage(0, 0);
    int nk = K >> 6;
    for (int ki = 0; ki < nk; ++ki) {
        asm volatile("s_waitcnt vmcnt(0)" ::: "memory");
        __builtin_amdgcn_s_barrier();
        __builtin_amdgcn_sched_barrier(0);
        int cur = ki & 1;
        if (ki + 1 < nk) stage((ki + 1) * 64, cur ^ 1);
#pragma unroll
        for (int kk = 0; kk < 2; ++kk) {
            bf16x8 af[4], bfr[4];
#pragma unroll
            for (int m = 0; m < 4; ++m)
                af[m] = *(const bf16x8*)&As[cur][(wr * 64 + m * 16 + lr) * 64 +
                                                (((kk * 4 + lg) ^ (lr & 7)) * 8)];
#pragma unroll
            for (int n = 0; n < 4; ++n)
                bfr[n] = *(const bf16x8*)&Bs[cur][(wc * 64 + n * 16 + lr) * 64 +
                                                 (((kk * 4 + lg) ^ (lr & 7)) * 8)];
#pragma unroll
            for (int m = 0; m < 4; ++m)
#pragma unroll
                for (int n = 0; n < 4; ++n)
                    acc[m][n] = __builtin_amdgcn_mfma_f32_16x16x32_bf16(af[m], bfr[n], acc[m][n], 0, 0, 0);
        }
    }
#pragma unroll
    for (int m = 0; m < 4; ++m) {
        int row = m0 + wr * 64 + m * 16 + lg * 4;
#pragma unroll
        for (int n = 0; n < 4; ++n) {
            int col = n0 + wc * 64 + n * 16 + lr;
            float* Cp = C + (size_t)row * N + col;
#pragma unroll
            for (int r = 0; r < 4; ++r)
                Cp[(size_t)r * N] = acc[m][n][r];
        }
    }
}

// ---------- GEMM (bf16 out): same structure, C stored as bf16 ----------
__global__ __launch_bounds__(256, 2) void gemm_bf16o(const u16* __restrict__ A,
                                                     const u16* __restrict__ BT,
                                                     u16* __restrict__ C, int N, int K) {
    __shared__ __align__(16) u16 As[2][128 * 64];
    __shared__ __align__(16) u16 Bs[2][128 * 64];
    int nwg = gridDim.x * gridDim.y;
    int bid = blockIdx.y * gridDim.x + blockIdx.x;
    int nb = (bid & 7) * (nwg >> 3) + (bid >> 3);
    int bx = nb % gridDim.x, by = nb / gridDim.x;

    int t = threadIdx.x;
    int w = t >> 6, l = t & 63;
    int wr = w >> 1, wc = w & 1;
    int lg = l >> 4, lr = l & 15;
    int m0 = by * 128, n0 = bx * 128;
    f32x4 acc[4][4] = {};

    size_t goff[4];
#pragma unroll
    for (int i = 0; i < 4; ++i) {
        int g = t + i * 256;
        goff[i] = (size_t)(g >> 3) * K * 2 + (size_t)(((g & 7) ^ ((g >> 3) & 7)) * 16);
    }
    const char* Ab = (const char*)A + (size_t)m0 * K * 2;
    const char* Bb = (const char*)BT + (size_t)n0 * K * 2;

    auto stage = [&](int kt, int buf) {
        char* Ad = (char*)As[buf] + t * 16;
        char* Bd = (char*)Bs[buf] + t * 16;
#pragma unroll
        for (int i = 0; i < 4; ++i) {
            gl16(Ab + (size_t)kt * 2 + goff[i], Ad + i * 4096);
            gl16(Bb + (size_t)kt * 2 + goff[i], Bd + i * 4096);
        }
    };

    stage(0, 0);
    int nk = K >> 6;
    for (int ki = 0; ki < nk; ++ki) {
        asm volatile("s_waitcnt vmcnt(0)" ::: "memory");
        __builtin_amdgcn_s_barrier();
        __builtin_amdgcn_sched_barrier(0);
        int cur = ki & 1;
        if (ki + 1 < nk) stage((ki + 1) * 64, cur ^ 1);
#pragma unroll
        for (int kk = 0; kk < 2; ++kk) {
            bf16x8 af[4], bfr[4];
#pragma unroll
            for (int m = 0; m < 4; ++m)
                af[m] = *(const bf16x8*)&As[cur][(wr * 64 + m * 16 + lr) * 64 +
                                                (((kk * 4 + lg) ^ (lr & 7)) * 8)];
#pragma unroll
            for (int n = 0; n < 4; ++n)
                bfr[n] = *(const bf16x8*)&Bs[cur][(wc * 64 + n * 16 + lr) * 64 +
                                                 (((kk * 4 + lg) ^ (lr & 7)) * 8)];
#pragma unroll
            for (int m = 0; m < 4; ++m)
#pragma unroll
                for (int n = 0; n < 4; ++n)
                    acc[m][n] = __builtin_amdgcn_mfma_f32_16x16x32_bf16(af[m], bfr[n], acc[m][n], 0, 0, 0);
        }
    }
#pragma unroll
    for (int m = 0; m < 4; ++m) {
        int row = m0 + wr * 64 + m * 16 + lg * 4;
#pragma unroll
        for (int n = 0; n < 4; ++n) {
            int col = n0 + wc * 64 + n * 16 + lr;
            u16* Cp = C + (size_t)row * N + col;
#pragma unroll
            for (int r = 0; r < 4; ++r)
                Cp[(size_t)r * N] = f2bf(acc[m][n][r]);
        }
    }
}

// ---------- fused rope_rms + transpose_v (both read bf16 qkv), one launch ----------
__global__ __launch_bounds__(256) void rope_tv(const u16* __restrict__ qkv,
                                               const float* __restrict__ cs,
                                               const float* __restrict__ sn,
                                               u16* __restrict__ qh, u16* __restrict__ kh,
                                               u16* __restrict__ vt) {
    int bz = blockIdx.x;
    int t = threadIdx.x;
    if (bz < 20480) {
        int task = bz * 4 + (t >> 6);
        int l = t & 63;
        const u16* in;
        u16* out;
        int tpos;
        float post = 1.0f;
        if (task < 65536) {               // q: 4096 rows * 16 heads
            int row = task >> 4, h = task & 15;
            in = qkv + (size_t)row * 3072 + h * 128;
            int b = row >> 11; tpos = row & 2047;
            out = qh + ((size_t)(b * NH_ + h) * T_ + tpos) * HD_;
            post = K2_;
        } else {                          // k: 4096 rows * 4 heads
            int t2 = task - 65536;
            int row = t2 >> 2, h = t2 & 3;
            in = qkv + (size_t)row * 3072 + 2048 + h * 128;
            int b = row >> 11; tpos = row & 2047;
            out = kh + ((size_t)(b * NKV_ + h) * T_ + tpos) * HD_;
        }
        float x1 = bf2f(in[l]), x2 = bf2f(in[l + 64]);
        float c = cs[tpos * 64 + l], s = sn[tpos * 64 + l];
        float o1 = x1 * c + x2 * s;
        float o2 = -x1 * s + x2 * c;
        float ss = o1 * o1 + o2 * o2;
#pragma unroll
        for (int m = 1; m < 64; m <<= 1) ss += __shfl_xor(ss, m);
        float r = rsqrtf(ss * (1.0f / 128.0f) + 1.1920929e-07f) * post;
        out[l] = f2bf(o1 * r);
        out[l + 64] = f2bf(o2 * r);
        return;
    }
    // transpose_v tile
    __shared__ u16 tile[32][34];
    int z = bz - 20480;                 // 0..2047 = x(64) * y(4) * bk(8)
    int t0 = (z & 63) * 32;
    int d0 = ((z >> 6) & 3) * 32;
    int bk = z >> 8;
    int b = bk >> 2, kvh = bk & 3;
    int tx = t & 31, ty = t >> 5;       // 32 x 8
#pragma unroll
    for (int i = 0; i < 4; ++i)
        tile[ty * 4 + i][tx] =
            qkv[(size_t)(b * 2048 + t0 + ty * 4 + i) * 3072 + 2560 + kvh * 128 + d0 + tx];
    __syncthreads();
#pragma unroll
    for (int i = 0; i < 4; ++i)
        vt[((size_t)bk * 128 + d0 + ty * 4 + i) * 2048 + t0 + tx] = tile[tx][ty * 4 + i];
}

// ---------- causal GQA flash attention: 8-wave blocks, K dbuf + V counted-vmcnt ----------
// + l-sum via ones-MFMA (matrix pipe), tree max. 384 blocks x 512 thr.
// LDS: K dbuf 32K + V single 16K + P 8K = 57344 B.
__global__ __launch_bounds__(512, 1) void attn(const u16* __restrict__ Q,
                                               const u16* __restrict__ Kk,
                                               const u16* __restrict__ V,
                                               u16* __restrict__ Y,
                                               u16* __restrict__ Opart,
                                               float2* __restrict__ Ml) {
    extern __shared__ __align__(16) u16 sm[];
    u16* Ks = sm;            // [2][64*128]  32 KB dbuf
    u16* Vs = sm + 16384;    // [128*64]     16 KB single
    u16* Pb = sm + 24576;    // [8][16*32]    8 KB, granule-XOR swizzled

    int bid = blockIdx.x;
    int xcd = bid & 7;
    int b = xcd >> 2, kvh = xcd & 3;
    int tk = bid >> 3;                         // 0..47
    int j, g0, g1, seg;
    bool split;
    if (tk < 16) {                             // whole short strip
        j = tk; g0 = 0; g1 = j + 1; split = false; seg = 0;
    } else if (tk < 32) {                      // seg0 of long strip: exactly 16 tiles
        j = tk; g0 = 0; g1 = 16; split = true; seg = 0;
    } else {                                   // seg1 of long strip
        j = 63 - tk; g0 = 16; g1 = j + 1; split = true; seg = 1;
    }
    int t = threadIdx.x;
    int w = t >> 6, l = t & 63;
    int lg = l >> 4, lr = l & 15;
    int hh = w & 3;
    int h = kvh * 4 + hh;
    int qw = j * 64 + (w >> 2) * 32;           // each wave: 32 rows

    const u16* Qp = Q + (size_t)(b * NH_ + h) * T_ * HD_;
    const u16* Kp = Kk + (size_t)(b * NKV_ + kvh) * T_ * HD_;
    const u16* Vp = V + (size_t)(b * NKV_ + kvh) * HD_ * T_;
    u16* Yp = Y + (size_t)(b * T_) * 2048 + h * HD_;
    u16* Pw = Pb + w * 512;

    size_t koff[2], voff[2];
#pragma unroll
    for (int i = 0; i < 2; ++i) {
        int g = t + i * 512;
        koff[i] = (size_t)(g >> 4) * 256 + (size_t)(((g & 15) ^ ((g >> 4) & 15)) * 16);
        voff[i] = (size_t)(g >> 3) * (T_ * 2) + (size_t)(((g & 7) ^ ((g >> 3) & 7)) * 16);
    }
    auto stageK = [&](int kv0, int buf) {
        const char* Kb = (const char*)Kp + (size_t)kv0 * 256;
        char* Kd = (char*)Ks + buf * 16384 + t * 16;
#pragma unroll
        for (int i = 0; i < 2; ++i) gl16(Kb + koff[i], Kd + i * 8192);
    };
    auto stageV = [&](int kv0) {
        const char* Vb = (const char*)Vp + (size_t)kv0 * 2;
        char* Vd = (char*)Vs + t * 16;
#pragma unroll
        for (int i = 0; i < 2; ++i) gl16(Vb + voff[i], Vd + i * 8192);
    };

    bf16x8 aq[2][4];
#pragma unroll
    for (int qf = 0; qf < 2; ++qf)
#pragma unroll
        for (int ch = 0; ch < 4; ++ch)
            aq[qf][ch] = *(const bf16x8*)(Qp + (size_t)(qw + qf * 16 + lr) * HD_ + ch * 32 + lg * 8);

    bf16x8 ones;
#pragma unroll
    for (int i = 0; i < 8; ++i) ones[i] = __builtin_bit_cast(__bf16, (u16)0x3F80);

    f32x4 acc[2][8] = {};
    f32x4 accl[2] = {};
    float m2[2] = {-1e30f, -1e30f};

    stageK(g0 * 64, 0);

    for (int gi = g0; gi < g1; ++gi) {
        asm volatile("s_waitcnt vmcnt(0)" ::: "memory");
        __builtin_amdgcn_s_barrier();
        __builtin_amdgcn_sched_barrier(0);
        int cur = (gi - g0) & 1;
        int kv0 = gi * 64;
        // V for THIS iter (issued first -> oldest in vmcnt order)
        stageV(kv0);
        __builtin_amdgcn_sched_barrier(0);
        // K prefetch for next iter (dummy restage on last iter keeps count at 2)
        int gn = (gi + 1 < g1) ? gi + 1 : g0;
        stageK(gn * 64, cur ^ 1);
        __builtin_amdgcn_sched_barrier(0);
        int kbase = cur * 8192;

        // ---- S^T = K Q^T (32 MFMA, K frags feed both qf) ----
        f32x4 sc[2][4] = {};
        __builtin_amdgcn_s_setprio(1);
#pragma unroll
        for (int ch = 0; ch < 4; ++ch)
#pragma unroll
            for (int kf = 0; kf < 4; ++kf) {
                bf16x8 bk = *(const bf16x8*)&Ks[kbase + (kf * 16 + lr) * 128 + (((ch * 4 + lg) ^ lr) * 8)];
                sc[0][kf] = __builtin_amdgcn_mfma_f32_16x16x32_bf16(bk, aq[0][ch], sc[0][kf], 0, 0, 0);
                sc[1][kf] = __builtin_amdgcn_mfma_f32_16x16x32_bf16(bk, aq[1][ch], sc[1][kf], 0, 0, 0);
            }
        __builtin_amdgcn_s_setprio(0);

        // ---- mask (diagonal tile only) ----
        if (kv0 + 63 > qw) {
#pragma unroll
            for (int qf = 0; qf < 2; ++qf) {
                int qrow = qw + qf * 16 + lr;
#pragma unroll
                for (int kf = 0; kf < 4; ++kf)
#pragma unroll
                    for (int r = 0; r < 4; ++r) {
                        int key = kv0 + kf * 16 + 4 * lg + r;
                        if (key > qrow) sc[qf][kf][r] = -1e38f;
                    }
            }
        }
        // ---- tree row-max (depth 4) + cross-lg reduce ----
        float mx[2];
#pragma unroll
        for (int qf = 0; qf < 2; ++qf) {
            float tm[4];
#pragma unroll
            for (int kf = 0; kf < 4; ++kf)
                tm[kf] = fmaxf(fmaxf(sc[qf][kf][0], sc[qf][kf][1]),
                               fmaxf(sc[qf][kf][2], sc[qf][kf][3]));
            float m = fmaxf(fmaxf(tm[0], tm[1]), fmaxf(tm[2], tm[3]));
            m = fmaxf(m, __shfl_xor(m, 16));
            m = fmaxf(m, __shfl_xor(m, 32));
            mx[qf] = m;
        }
        // ---- defer-max rescale (THR=8, log2 domain) ----
        bool upd = (mx[0] > m2[0] + 8.0f) || (mx[1] > m2[1] + 8.0f);
        if (__any(upd)) {
#pragma unroll
            for (int qf = 0; qf < 2; ++qf) {
                float mn = fmaxf(m2[qf], mx[qf]);
                float rs = exp2f(m2[qf] - mn);
                m2[qf] = mn;
                float rs4[4];
#pragma unroll
                for (int r = 0; r < 4; ++r) rs4[r] = __shfl(rs, 4 * lg + r, 16);
#pragma unroll
                for (int oc = 0; oc < 8; ++oc)
#pragma unroll
                    for (int r = 0; r < 4; ++r) acc[qf][oc][r] *= rs4[r];
#pragma unroll
                for (int r = 0; r < 4; ++r) accl[qf][r] *= rs4[r];
            }
        }
        // ---- p = 2^(s-m), four-pass P through 1KB/wave buffer ----
        bf16x8 ap[2][2];
#pragma unroll
        for (int kk = 0; kk < 2; ++kk) {
#pragma unroll
            for (int qf = 0; qf < 2; ++qf) {
#pragma unroll
                for (int kfl = 0; kfl < 2; ++kfl) {
                    int kf = kk * 2 + kfl;
                    float p0 = exp2f(sc[qf][kf][0] - m2[qf]);
                    float p1 = exp2f(sc[qf][kf][1] - m2[qf]);
                    float p2 = exp2f(sc[qf][kf][2] - m2[qf]);
                    float p3 = exp2f(sc[qf][kf][3] - m2[qf]);
                    uint2v pk;
                    pk[0] = cvtpk(p0, p1);
                    pk[1] = cvtpk(p2, p3);
                    int g = 2 * kfl + (lg >> 1);
                    *(uint2v*)&Pw[lr * 32 + ((g ^ (lr & 3)) * 8) + (lg & 1) * 4] = pk;
                }
                ap[qf][kk] = *(const bf16x8*)&Pw[lr * 32 + ((lg ^ (lr & 3)) * 8)];
            }
        }
        // ---- V(cur) ready: vmcnt(2) leaves the 2 K-prefetch loads in flight ----
        asm volatile("s_waitcnt vmcnt(2)" ::: "memory");
        __builtin_amdgcn_s_barrier();
        __builtin_amdgcn_sched_barrier(0);

        // ---- O += P V (32 MFMA) + l-sum via ones-MFMA (4 MFMA) ----
        __builtin_amdgcn_s_setprio(1);
#pragma unroll
        for (int qf = 0; qf < 2; ++qf)
#pragma unroll
            for (int kk = 0; kk < 2; ++kk)
                accl[qf] = __builtin_amdgcn_mfma_f32_16x16x32_bf16(ap[qf][kk], ones, accl[qf], 0, 0, 0);
#pragma unroll
        for (int oc = 0; oc < 8; ++oc)
#pragma unroll
            for (int kk = 0; kk < 2; ++kk) {
                bf16x8 bv = *(const bf16x8*)&Vs[(oc * 16 + lr) * 64 +
                                                (((kk * 4 + lg) ^ (lr & 7)) * 8)];
                acc[0][oc] = __builtin_amdgcn_mfma_f32_16x16x32_bf16(ap[0][kk], bv, acc[0][oc], 0, 0, 0);
                acc[1][oc] = __builtin_amdgcn_mfma_f32_16x16x32_bf16(ap[1][kk], bv, acc[1][oc], 0, 0, 0);
            }
        __builtin_amdgcn_s_setprio(0);
    }
    // drain the dummy K prefetch before epilogue
    asm volatile("s_waitcnt vmcnt(0)" ::: "memory");

    if (!split) {
        // ---- final epilogue: normalize + bf16 store (l already per-row in accl) ----
#pragma unroll
        for (int qf = 0; qf < 2; ++qf) {
            float inv4[4];
#pragma unroll
            for (int r = 0; r < 4; ++r) inv4[r] = 1.0f / accl[qf][r];
#pragma unroll
            for (int oc = 0; oc < 8; ++oc)
#pragma unroll
                for (int r = 0; r < 4; ++r)
                    Yp[(size_t)(qw + qf * 16 + 4 * lg + r) * 2048 + oc * 16 + lr] =
                        f2bf(acc[qf][oc][r] * inv4[r]);
        }
    } else {
        // ---- partial epilogue: unnormalized bf16 O [64][128] + per-row (m,l) ----
        int s16 = j - 16;
        size_t pbase = (((size_t)(xcd * 16 + s16) * 4 + hh) * 2 + seg);
        u16* Op = Opart + pbase * 8192;
        float2* mlp = Ml + pbase * 64;
        int ro = (w >> 2) * 32;
#pragma unroll
        for (int qf = 0; qf < 2; ++qf)
#pragma unroll
            for (int oc = 0; oc < 8; ++oc)
#pragma unroll
                for (int r = 0; r < 4; ++r)
                    Op[(ro + qf * 16 + 4 * lg + r) * 128 + oc * 16 + lr] = f2bf(acc[qf][oc][r]);
        // lane where lr == 4*lg+r holds BOTH m2 (row=lr) and accl[.][r] (row=4lg+r=lr)
        if ((lr >> 2) == lg) {
            int r = lr & 3;
            mlp[ro + lr] = float2{m2[0], accl[0][r]};
            mlp[ro + 16 + lr] = float2{m2[1], accl[1][r]};
        }
    }
}

// ---------- combine: merge the two KV-segments of each long strip ----------
__global__ __launch_bounds__(256) void combine(const u16* __restrict__ Opart,
                                               const float2* __restrict__ Ml,
                                               u16* __restrict__ Y) {
    int blk = blockIdx.x;
    int hh = blk & 3;
    int s16 = (blk >> 2) & 15;
    int xcd = blk >> 6;
    int b = xcd >> 2, kvh = xcd & 3, h = kvh * 4 + hh;
    size_t p0 = (size_t)blk * 2;
    size_t p1 = p0 + 1;
    int t = threadIdx.x;
    int row = t >> 2, c0 = (t & 3) * 32;
    float2 a = Ml[p0 * 64 + row];
    float2 c = Ml[p1 * 64 + row];
    float M = fmaxf(a.x, c.x);
    float w1 = exp2f(a.x - M), w2 = exp2f(c.x - M);
    float inv = 1.0f / (w1 * a.y + w2 * c.y);
    const u16* O1 = Opart + p0 * 8192 + row * 128 + c0;
    const u16* O2 = Opart + p1 * 8192 + row * 128 + c0;
    int qrow = (16 + s16) * 64 + row;
    u16* Yp = Y + ((size_t)(b * T_) + qrow) * 2048 + h * HD_ + c0;
#pragma unroll
    for (int v = 0; v < 4; ++v) {
        u16x8 v1 = *(const u16x8*)(O1 + v * 8);
        u16x8 v2 = *(const u16x8*)(O2 + v * 8);
        u16x8 o;
#pragma unroll
        for (int i = 0; i < 8; ++i)
            o[i] = f2bf((w1 * bf2f(v1[i]) + w2 * bf2f(v2[i])) * inv);
        *(u16x8*)(Yp + v * 8) = o;
    }
}

extern "C" void kernel_launch(void* const* d_in, const int* in_sizes, int n_in,
                              void* d_out, int out_size, void* d_ws, size_t ws_size,
                              hipStream_t stream) {
    const float* x    = (const float*)d_in[0];
    const float* cosT = (const float*)d_in[1];
    const float* sinT = (const float*)d_in[2];
    const float* wq   = (const float*)d_in[3];
    const float* wk   = (const float*)d_in[4];
    const float* wv   = (const float*)d_in[5];
    const float* wo   = (const float*)d_in[6];
    float* out = (float*)d_out;

    char* ws = (char*)d_ws;
    u16*    wqkvT = (u16*)(ws);                      // [3072][2048] bf16
    u16*    woT   = (u16*)(ws + 12582912);           // [2048][2048] bf16
    u16*    xb    = (u16*)(ws + 20971520);           // [4096][2048] bf16
    u16*    qkv   = (u16*)(ws + 37748736);           // [4096][3072] bf16 (ends 62914560)
    u16*    opart = (u16*)(ws + 62914560);           // 1024 x [64][128] bf16 partials (16MB)
    float2* mlbuf = (float2*)(ws + 79691776);        // 1024 x [64] float2 (512KB)
    u16*    qh    = (u16*)(ws + 88080384);           // [2][16][2048][128] bf16
    u16*    kh    = (u16*)(ws + 104857600);          // [2][4][2048][128] bf16
    u16*    vt    = (u16*)(ws + 109051904);          // [2][4][128][2048] bf16 (V^T)
    u16*    y     = xb;                              // reuse (xb dead after GEMM1)

    hipFuncSetAttribute(reinterpret_cast<const void*>(&attn),
                        hipFuncAttributeMaxDynamicSharedMemorySize, 57344);

    prepass<<<18432, 256, 0, stream>>>(wq, wk, wv, wo, (const float4*)x, wqkvT, woT, xb);

    gemm_bf16o<<<dim3(24, 32), 256, 0, stream>>>(xb, wqkvT, qkv, 3072, 2048);

    rope_tv<<<22528, 256, 0, stream>>>(qkv, cosT, sinT, qh, kh, vt);

    attn<<<384, 512, 57344, stream>>>(qh, kh, vt, y, opart, mlbuf);
    combine<<<512, 256, 0, stream>>>(opart, mlbuf, y);

    gemm_bf16<<<dim3(16, 32), 256, 0, stream>>>(y, woT, out, 2048, 2048);
}

// Round 21
// 189.982 us; speedup vs baseline: 1.0069x; 1.0069x over previous
//
#include <hip/hip_runtime.h>
#include <hip/hip_bf16.h>
#include <cstdint>

typedef unsigned short u16;
typedef __bf16 bf16x8 __attribute__((ext_vector_type(8)));
typedef float f32x4 __attribute__((ext_vector_type(4)));
typedef unsigned short u16x4 __attribute__((ext_vector_type(4)));
typedef unsigned short u16x8 __attribute__((ext_vector_type(8)));
typedef unsigned uint2v __attribute__((ext_vector_type(2)));

#define B_ 2
#define T_ 2048
#define C_ 2048
#define NH_ 16
#define NKV_ 4
#define HD_ 128
// (1/sqrt(128)) * log2(e) — folded into Q
#define K2_ 0.12752004650581538f

__device__ __forceinline__ u16 f2bf(float f) {
    unsigned u = __builtin_bit_cast(unsigned, f);
    unsigned r = u + 0x7FFFu + ((u >> 16) & 1u);
    return (u16)(r >> 16);
}

__device__ __forceinline__ float bf2f(u16 v) {
    unsigned u = ((unsigned)v) << 16;
    return __builtin_bit_cast(float, u);
}

__device__ __forceinline__ unsigned cvtpk(float a, float b) {
    unsigned r;
    asm("v_cvt_pk_bf16_f32 %0, %1, %2" : "=v"(r) : "v"(a), "v"(b));
    return r;
}

__device__ __forceinline__ void gl16(const void* g, void* l) {
    auto gp = reinterpret_cast<const __attribute__((address_space(1))) unsigned*>(
        reinterpret_cast<uintptr_t>(g));
    auto lp = reinterpret_cast<__attribute__((address_space(3))) unsigned*>(
        reinterpret_cast<uintptr_t>(l));
    __builtin_amdgcn_global_load_lds(gp, lp, 16, 0, 0);
}

// ---------- fused prepass: 4 weight transposes + x convert, one launch ----------
__global__ __launch_bounds__(256) void prepass(const float* __restrict__ wq,
                                               const float* __restrict__ wk,
                                               const float* __restrict__ wv,
                                               const float* __restrict__ wo,
                                               const float4* __restrict__ x,
                                               u16* __restrict__ wqkvT,
                                               u16* __restrict__ woT,
                                               u16* __restrict__ xb) {
    int bz = blockIdx.x;
    int t = threadIdx.x;
    if (bz >= 10240) {  // convert x
        int i = (bz - 10240) * 256 + t;
        float4 v = x[i];
        u16x4 o;
        o[0] = f2bf(v.x); o[1] = f2bf(v.y); o[2] = f2bf(v.z); o[3] = f2bf(v.w);
        ((u16x4*)xb)[i] = o;
        return;
    }
    __shared__ float tile[32][33];
    const float* in;
    u16* out;
    int N, bx, by;
    if (bz < 4096)      { in = wq; out = wqkvT;                      N = 2048; bx = bz & 63; by = bz >> 6; }
    else if (bz < 5120) { int z = bz - 4096; in = wk; out = wqkvT + (size_t)2048 * 2048; N = 512; bx = z & 15; by = z >> 4; }
    else if (bz < 6144) { int z = bz - 5120; in = wv; out = wqkvT + (size_t)2560 * 2048; N = 512; bx = z & 15; by = z >> 4; }
    else                { int z = bz - 6144; in = wo; out = woT;     N = 2048; bx = z & 63; by = z >> 6; }
    int n0 = bx * 32, k0 = by * 32;
    int tx = t & 31, ty = t >> 5;  // 32 x 8
#pragma unroll
    for (int i = 0; i < 4; ++i)
        tile[ty * 4 + i][tx] = in[(size_t)(k0 + ty * 4 + i) * N + n0 + tx];
    __syncthreads();
#pragma unroll
    for (int i = 0; i < 4; ++i)
        out[(size_t)(n0 + ty * 4 + i) * 2048 + k0 + tx] = f2bf(tile[tx][ty * 4 + i]);
}

// ---------- GEMM (f32 out, 128^2 2-phase): used for gemm2 ----------
__global__ __launch_bounds__(256, 2) void gemm_bf16(const u16* __restrict__ A,
                                                    const u16* __restrict__ BT,
                                                    float* __restrict__ C, int N, int K) {
    __shared__ __align__(16) u16 As[2][128 * 64];
    __shared__ __align__(16) u16 Bs[2][128 * 64];
    int nwg = gridDim.x * gridDim.y;
    int bid = blockIdx.y * gridDim.x + blockIdx.x;
    int nb = (bid & 7) * (nwg >> 3) + (bid >> 3);
    int bx = nb % gridDim.x, by = nb / gridDim.x;

    int t = threadIdx.x;
    int w = t >> 6, l = t & 63;
    int wr = w >> 1, wc = w & 1;
    int lg = l >> 4, lr = l & 15;
    int m0 = by * 128, n0 = bx * 128;
    f32x4 acc[4][4] = {};

    size_t goff[4];
#pragma unroll
    for (int i = 0; i < 4; ++i) {
        int g = t + i * 256;
        goff[i] = (size_t)(g >> 3) * K * 2 + (size_t)(((g & 7) ^ ((g >> 3) & 7)) * 16);
    }
    const char* Ab = (const char*)A + (size_t)m0 * K * 2;
    const char* Bb = (const char*)BT + (size_t)n0 * K * 2;

    auto stage = [&](int kt, int buf) {
        char* Ad = (char*)As[buf] + t * 16;
        char* Bd = (char*)Bs[buf] + t * 16;
#pragma unroll
        for (int i = 0; i < 4; ++i) {
            gl16(Ab + (size_t)kt * 2 + goff[i], Ad + i * 4096);
            gl16(Bb + (size_t)kt * 2 + goff[i], Bd + i * 4096);
        }
    };

    stage(0, 0);
    int nk = K >> 6;
    for (int ki = 0; ki < nk; ++ki) {
        asm volatile("s_waitcnt vmcnt(0)" ::: "memory");
        __builtin_amdgcn_s_barrier();
        __builtin_amdgcn_sched_barrier(0);
        int cur = ki & 1;
        if (ki + 1 < nk) stage((ki + 1) * 64, cur ^ 1);
#pragma unroll
        for (int kk = 0; kk < 2; ++kk) {
            bf16x8 af[4], bfr[4];
#pragma unroll
            for (int m = 0; m < 4; ++m)
                af[m] = *(const bf16x8*)&As[cur][(wr * 64 + m * 16 + lr) * 64 +
                                                (((kk * 4 + lg) ^ (lr & 7)) * 8)];
#pragma unroll
            for (int n = 0; n < 4; ++n)
                bfr[n] = *(const bf16x8*)&Bs[cur][(wc * 64 + n * 16 + lr) * 64 +
                                                 (((kk * 4 + lg) ^ (lr & 7)) * 8)];
#pragma unroll
            for (int m = 0; m < 4; ++m)
#pragma unroll
                for (int n = 0; n < 4; ++n)
                    acc[m][n] = __builtin_amdgcn_mfma_f32_16x16x32_bf16(af[m], bfr[n], acc[m][n], 0, 0, 0);
        }
    }
#pragma unroll
    for (int m = 0; m < 4; ++m) {
        int row = m0 + wr * 64 + m * 16 + lg * 4;
#pragma unroll
        for (int n = 0; n < 4; ++n) {
            int col = n0 + wc * 64 + n * 16 + lr;
            float* Cp = C + (size_t)row * N + col;
#pragma unroll
            for (int r = 0; r < 4; ++r)
                Cp[(size_t)r * N] = acc[m][n][r];
        }
    }
}

// ---------- GEMM (bf16 out): same structure, C stored as bf16 ----------
__global__ __launch_bounds__(256, 2) void gemm_bf16o(const u16* __restrict__ A,
                                                     const u16* __restrict__ BT,
                                                     u16* __restrict__ C, int N, int K) {
    __shared__ __align__(16) u16 As[2][128 * 64];
    __shared__ __align__(16) u16 Bs[2][128 * 64];
    int nwg = gridDim.x * gridDim.y;
    int bid = blockIdx.y * gridDim.x + blockIdx.x;
    int nb = (bid & 7) * (nwg >> 3) + (bid >> 3);
    int bx = nb % gridDim.x, by = nb / gridDim.x;

    int t = threadIdx.x;
    int w = t >> 6, l = t & 63;
    int wr = w >> 1, wc = w & 1;
    int lg = l >> 4, lr = l & 15;
    int m0 = by * 128, n0 = bx * 128;
    f32x4 acc[4][4] = {};

    size_t goff[4];
#pragma unroll
    for (int i = 0; i < 4; ++i) {
        int g = t + i * 256;
        goff[i] = (size_t)(g >> 3) * K * 2 + (size_t)(((g & 7) ^ ((g >> 3) & 7)) * 16);
    }
    const char* Ab = (const char*)A + (size_t)m0 * K * 2;
    const char* Bb = (const char*)BT + (size_t)n0 * K * 2;

    auto stage = [&](int kt, int buf) {
        char* Ad = (char*)As[buf] + t * 16;
        char* Bd = (char*)Bs[buf] + t * 16;
#pragma unroll
        for (int i = 0; i < 4; ++i) {
            gl16(Ab + (size_t)kt * 2 + goff[i], Ad + i * 4096);
            gl16(Bb + (size_t)kt * 2 + goff[i], Bd + i * 4096);
        }
    };

    stage(0, 0);
    int nk = K >> 6;
    for (int ki = 0; ki < nk; ++ki) {
        asm volatile("s_waitcnt vmcnt(0)" ::: "memory");
        __builtin_amdgcn_s_barrier();
        __builtin_amdgcn_sched_barrier(0);
        int cur = ki & 1;
        if (ki + 1 < nk) stage((ki + 1) * 64, cur ^ 1);
#pragma unroll
        for (int kk = 0; kk < 2; ++kk) {
            bf16x8 af[4], bfr[4];
#pragma unroll
            for (int m = 0; m < 4; ++m)
                af[m] = *(const bf16x8*)&As[cur][(wr * 64 + m * 16 + lr) * 64 +
                                                (((kk * 4 + lg) ^ (lr & 7)) * 8)];
#pragma unroll
            for (int n = 0; n < 4; ++n)
                bfr[n] = *(const bf16x8*)&Bs[cur][(wc * 64 + n * 16 + lr) * 64 +
                                                 (((kk * 4 + lg) ^ (lr & 7)) * 8)];
#pragma unroll
            for (int m = 0; m < 4; ++m)
#pragma unroll
                for (int n = 0; n < 4; ++n)
                    acc[m][n] = __builtin_amdgcn_mfma_f32_16x16x32_bf16(af[m], bfr[n], acc[m][n], 0, 0, 0);
        }
    }
#pragma unroll
    for (int m = 0; m < 4; ++m) {
        int row = m0 + wr * 64 + m * 16 + lg * 4;
#pragma unroll
        for (int n = 0; n < 4; ++n) {
            int col = n0 + wc * 64 + n * 16 + lr;
            u16* Cp = C + (size_t)row * N + col;
#pragma unroll
            for (int r = 0; r < 4; ++r)
                Cp[(size_t)r * N] = f2bf(acc[m][n][r]);
        }
    }
}

// ---------- fused rope_rms + transpose_v (both read bf16 qkv), one launch ----------
__global__ __launch_bounds__(256) void rope_tv(const u16* __restrict__ qkv,
                                               const float* __restrict__ cs,
                                               const float* __restrict__ sn,
                                               u16* __restrict__ qh, u16* __restrict__ kh,
                                               u16* __restrict__ vt) {
    int bz = blockIdx.x;
    int t = threadIdx.x;
    if (bz < 20480) {
        int task = bz * 4 + (t >> 6);
        int l = t & 63;
        const u16* in;
        u16* out;
        int tpos;
        float post = 1.0f;
        if (task < 65536) {               // q: 4096 rows * 16 heads
            int row = task >> 4, h = task & 15;
            in = qkv + (size_t)row * 3072 + h * 128;
            int b = row >> 11; tpos = row & 2047;
            out = qh + ((size_t)(b * NH_ + h) * T_ + tpos) * HD_;
            post = K2_;
        } else {                          // k: 4096 rows * 4 heads
            int t2 = task - 65536;
            int row = t2 >> 2, h = t2 & 3;
            in = qkv + (size_t)row * 3072 + 2048 + h * 128;
            int b = row >> 11; tpos = row & 2047;
            out = kh + ((size_t)(b * NKV_ + h) * T_ + tpos) * HD_;
        }
        float x1 = bf2f(in[l]), x2 = bf2f(in[l + 64]);
        float c = cs[tpos * 64 + l], s = sn[tpos * 64 + l];
        float o1 = x1 * c + x2 * s;
        float o2 = -x1 * s + x2 * c;
        float ss = o1 * o1 + o2 * o2;
#pragma unroll
        for (int m = 1; m < 64; m <<= 1) ss += __shfl_xor(ss, m);
        float r = rsqrtf(ss * (1.0f / 128.0f) + 1.1920929e-07f) * post;
        out[l] = f2bf(o1 * r);
        out[l + 64] = f2bf(o2 * r);
        return;
    }
    // transpose_v tile
    __shared__ u16 tile[32][34];
    int z = bz - 20480;                 // 0..2047 = x(64) * y(4) * bk(8)
    int t0 = (z & 63) * 32;
    int d0 = ((z >> 6) & 3) * 32;
    int bk = z >> 8;
    int b = bk >> 2, kvh = bk & 3;
    int tx = t & 31, ty = t >> 5;       // 32 x 8
#pragma unroll
    for (int i = 0; i < 4; ++i)
        tile[ty * 4 + i][tx] =
            qkv[(size_t)(b * 2048 + t0 + ty * 4 + i) * 3072 + 2560 + kvh * 128 + d0 + tx];
    __syncthreads();
#pragma unroll
    for (int i = 0; i < 4; ++i)
        vt[((size_t)bk * 128 + d0 + ty * 4 + i) * 2048 + t0 + tx] = tile[tx][ty * 4 + i];
}

// ---------- causal GQA flash attention: 8-wave blocks, FULL K+V dbuf, single barrier/iter ----------
// 384 blocks x 512 thr, r15 split task map. LDS: K dbuf 32K + V dbuf 32K + P 8K = 73728 B.
// Per iter: ONE vmcnt(0)+barrier (K(gi),V(gi) staged last iter), stage K/V(gi+1) -> buf^1,
// then compute with zero mid-iter syncs (P write->read is same-wave DS, in-order).
__global__ __launch_bounds__(512, 1) void attn(const u16* __restrict__ Q,
                                               const u16* __restrict__ Kk,
                                               const u16* __restrict__ V,
                                               u16* __restrict__ Y,
                                               u16* __restrict__ Opart,
                                               float2* __restrict__ Ml) {
    extern __shared__ __align__(16) u16 sm[];
    u16* Ks = sm;            // [2][64*128]  32 KB dbuf
    u16* Vs = sm + 16384;    // [2][128*64]  32 KB dbuf
    u16* Pb = sm + 32768;    // [8][16*32]    8 KB, granule-XOR swizzled

    int bid = blockIdx.x;
    int xcd = bid & 7;
    int b = xcd >> 2, kvh = xcd & 3;
    int tk = bid >> 3;                         // 0..47
    int j, g0, g1, seg;
    bool split;
    if (tk < 16) {                             // whole short strip
        j = tk; g0 = 0; g1 = j + 1; split = false; seg = 0;
    } else if (tk < 32) {                      // seg0 of long strip: exactly 16 tiles
        j = tk; g0 = 0; g1 = 16; split = true; seg = 0;
    } else {                                   // seg1 of long strip
        j = 63 - tk; g0 = 16; g1 = j + 1; split = true; seg = 1;
    }
    int t = threadIdx.x;
    int w = t >> 6, l = t & 63;
    int lg = l >> 4, lr = l & 15;
    int hh = w & 3;
    int h = kvh * 4 + hh;
    int qw = j * 64 + (w >> 2) * 32;           // each wave: 32 rows

    const u16* Qp = Q + (size_t)(b * NH_ + h) * T_ * HD_;
    const u16* Kp = Kk + (size_t)(b * NKV_ + kvh) * T_ * HD_;
    const u16* Vp = V + (size_t)(b * NKV_ + kvh) * HD_ * T_;
    u16* Yp = Y + (size_t)(b * T_) * 2048 + h * HD_;
    u16* Pw = Pb + w * 512;

    size_t koff[2], voff[2];
#pragma unroll
    for (int i = 0; i < 2; ++i) {
        int g = t + i * 512;
        koff[i] = (size_t)(g >> 4) * 256 + (size_t)(((g & 15) ^ ((g >> 4) & 15)) * 16);
        voff[i] = (size_t)(g >> 3) * (T_ * 2) + (size_t)(((g & 7) ^ ((g >> 3) & 7)) * 16);
    }
    auto stageK = [&](int kv0, int buf) {
        const char* Kb = (const char*)Kp + (size_t)kv0 * 256;
        char* Kd = (char*)Ks + buf * 16384 + t * 16;
#pragma unroll
        for (int i = 0; i < 2; ++i) gl16(Kb + koff[i], Kd + i * 8192);
    };
    auto stageV = [&](int kv0, int buf) {
        const char* Vb = (const char*)Vp + (size_t)kv0 * 2;
        char* Vd = (char*)Vs + buf * 16384 + t * 16;
#pragma unroll
        for (int i = 0; i < 2; ++i) gl16(Vb + voff[i], Vd + i * 8192);
    };

    bf16x8 aq[2][4];
#pragma unroll
    for (int qf = 0; qf < 2; ++qf)
#pragma unroll
        for (int ch = 0; ch < 4; ++ch)
            aq[qf][ch] = *(const bf16x8*)(Qp + (size_t)(qw + qf * 16 + lr) * HD_ + ch * 32 + lg * 8);

    bf16x8 ones;
#pragma unroll
    for (int i = 0; i < 8; ++i) ones[i] = __builtin_bit_cast(__bf16, (u16)0x3F80);

    f32x4 acc[2][8] = {};
    f32x4 accl[2] = {};
    float m2[2] = {-1e30f, -1e30f};

    stageK(g0 * 64, 0);
    stageV(g0 * 64, 0);

    for (int gi = g0; gi < g1; ++gi) {
        asm volatile("s_waitcnt vmcnt(0)" ::: "memory");
        __builtin_amdgcn_s_barrier();
        __builtin_amdgcn_sched_barrier(0);
        int cur = (gi - g0) & 1;
        int kv0 = gi * 64;
        // stage next iter's K AND V into buf^1 (dummy restage on last iter)
        int gn = (gi + 1 < g1) ? gi + 1 : g0;
        stageK(gn * 64, cur ^ 1);
        stageV(gn * 64, cur ^ 1);
        __builtin_amdgcn_sched_barrier(0);
        int kbase = cur * 8192;

        // ---- S^T = K Q^T (32 MFMA, K frags feed both qf) ----
        f32x4 sc[2][4] = {};
        __builtin_amdgcn_s_setprio(1);
#pragma unroll
        for (int ch = 0; ch < 4; ++ch)
#pragma unroll
            for (int kf = 0; kf < 4; ++kf) {
                bf16x8 bk = *(const bf16x8*)&Ks[kbase + (kf * 16 + lr) * 128 + (((ch * 4 + lg) ^ lr) * 8)];
                sc[0][kf] = __builtin_amdgcn_mfma_f32_16x16x32_bf16(bk, aq[0][ch], sc[0][kf], 0, 0, 0);
                sc[1][kf] = __builtin_amdgcn_mfma_f32_16x16x32_bf16(bk, aq[1][ch], sc[1][kf], 0, 0, 0);
            }
        __builtin_amdgcn_s_setprio(0);

        // ---- mask (diagonal tile only) ----
        if (kv0 + 63 > qw) {
#pragma unroll
            for (int qf = 0; qf < 2; ++qf) {
                int qrow = qw + qf * 16 + lr;
#pragma unroll
                for (int kf = 0; kf < 4; ++kf)
#pragma unroll
                    for (int r = 0; r < 4; ++r) {
                        int key = kv0 + kf * 16 + 4 * lg + r;
                        if (key > qrow) sc[qf][kf][r] = -1e38f;
                    }
            }
        }
        // ---- tree row-max (depth 4) + cross-lg reduce ----
        float mx[2];
#pragma unroll
        for (int qf = 0; qf < 2; ++qf) {
            float tm[4];
#pragma unroll
            for (int kf = 0; kf < 4; ++kf)
                tm[kf] = fmaxf(fmaxf(sc[qf][kf][0], sc[qf][kf][1]),
                               fmaxf(sc[qf][kf][2], sc[qf][kf][3]));
            float m = fmaxf(fmaxf(tm[0], tm[1]), fmaxf(tm[2], tm[3]));
            m = fmaxf(m, __shfl_xor(m, 16));
            m = fmaxf(m, __shfl_xor(m, 32));
            mx[qf] = m;
        }
        // ---- defer-max rescale (THR=8, log2 domain) ----
        bool upd = (mx[0] > m2[0] + 8.0f) || (mx[1] > m2[1] + 8.0f);
        if (__any(upd)) {
#pragma unroll
            for (int qf = 0; qf < 2; ++qf) {
                float mn = fmaxf(m2[qf], mx[qf]);
                float rs = exp2f(m2[qf] - mn);
                m2[qf] = mn;
                float rs4[4];
#pragma unroll
                for (int r = 0; r < 4; ++r) rs4[r] = __shfl(rs, 4 * lg + r, 16);
#pragma unroll
                for (int oc = 0; oc < 8; ++oc)
#pragma unroll
                    for (int r = 0; r < 4; ++r) acc[qf][oc][r] *= rs4[r];
#pragma unroll
                for (int r = 0; r < 4; ++r) accl[qf][r] *= rs4[r];
            }
        }
        // ---- p = 2^(s-m), four-pass P through 1KB/wave buffer ----
        bf16x8 ap[2][2];
#pragma unroll
        for (int kk = 0; kk < 2; ++kk) {
#pragma unroll
            for (int qf = 0; qf < 2; ++qf) {
#pragma unroll
                for (int kfl = 0; kfl < 2; ++kfl) {
                    int kf = kk * 2 + kfl;
                    float p0 = exp2f(sc[qf][kf][0] - m2[qf]);
                    float p1 = exp2f(sc[qf][kf][1] - m2[qf]);
                    float p2 = exp2f(sc[qf][kf][2] - m2[qf]);
                    float p3 = exp2f(sc[qf][kf][3] - m2[qf]);
                    uint2v pk;
                    pk[0] = cvtpk(p0, p1);
                    pk[1] = cvtpk(p2, p3);
                    int g = 2 * kfl + (lg >> 1);
                    *(uint2v*)&Pw[lr * 32 + ((g ^ (lr & 3)) * 8) + (lg & 1) * 4] = pk;
                }
                ap[qf][kk] = *(const bf16x8*)&Pw[lr * 32 + ((lg ^ (lr & 3)) * 8)];
            }
        }
        // ---- O += P V (32 MFMA) + l-sum via ones-MFMA (4 MFMA); V from buf cur ----
        __builtin_amdgcn_s_setprio(1);
#pragma unroll
        for (int qf = 0; qf < 2; ++qf)
#pragma unroll
            for (int kk = 0; kk < 2; ++kk)
                accl[qf] = __builtin_amdgcn_mfma_f32_16x16x32_bf16(ap[qf][kk], ones, accl[qf], 0, 0, 0);
#pragma unroll
        for (int oc = 0; oc < 8; ++oc)
#pragma unroll
            for (int kk = 0; kk < 2; ++kk) {
                bf16x8 bv = *(const bf16x8*)&Vs[kbase + (oc * 16 + lr) * 64 +
                                                (((kk * 4 + lg) ^ (lr & 7)) * 8)];
                acc[0][oc] = __builtin_amdgcn_mfma_f32_16x16x32_bf16(ap[0][kk], bv, acc[0][oc], 0, 0, 0);
                acc[1][oc] = __builtin_amdgcn_mfma_f32_16x16x32_bf16(ap[1][kk], bv, acc[1][oc], 0, 0, 0);
            }
        __builtin_amdgcn_s_setprio(0);
    }
    // drain the dummy prefetch before epilogue
    asm volatile("s_waitcnt vmcnt(0)" ::: "memory");

    if (!split) {
        // ---- final epilogue: normalize + bf16 store (l already per-row in accl) ----
#pragma unroll
        for (int qf = 0; qf < 2; ++qf) {
            float inv4[4];
#pragma unroll
            for (int r = 0; r < 4; ++r) inv4[r] = 1.0f / accl[qf][r];
#pragma unroll
            for (int oc = 0; oc < 8; ++oc)
#pragma unroll
                for (int r = 0; r < 4; ++r)
                    Yp[(size_t)(qw + qf * 16 + 4 * lg + r) * 2048 + oc * 16 + lr] =
                        f2bf(acc[qf][oc][r] * inv4[r]);
        }
    } else {
        // ---- partial epilogue: unnormalized bf16 O [64][128] + per-row (m,l) ----
        int s16 = j - 16;
        size_t pbase = (((size_t)(xcd * 16 + s16) * 4 + hh) * 2 + seg);
        u16* Op = Opart + pbase * 8192;
        float2* mlp = Ml + pbase * 64;
        int ro = (w >> 2) * 32;
#pragma unroll
        for (int qf = 0; qf < 2; ++qf)
#pragma unroll
            for (int oc = 0; oc < 8; ++oc)
#pragma unroll
                for (int r = 0; r < 4; ++r)
                    Op[(ro + qf * 16 + 4 * lg + r) * 128 + oc * 16 + lr] = f2bf(acc[qf][oc][r]);
        // lane where lr == 4*lg+r holds BOTH m2 (row=lr) and accl[.][r] (row=4lg+r=lr)
        if ((lr >> 2) == lg) {
            int r = lr & 3;
            mlp[ro + lr] = float2{m2[0], accl[0][r]};
            mlp[ro + 16 + lr] = float2{m2[1], accl[1][r]};
        }
    }
}

// ---------- combine: merge the two KV-segments of each long strip ----------
__global__ __launch_bounds__(256) void combine(const u16* __restrict__ Opart,
                                               const float2* __restrict__ Ml,
                                               u16* __restrict__ Y) {
    int blk = blockIdx.x;
    int hh = blk & 3;
    int s16 = (blk >> 2) & 15;
    int xcd = blk >> 6;
    int b = xcd >> 2, kvh = xcd & 3, h = kvh * 4 + hh;
    size_t p0 = (size_t)blk * 2;
    size_t p1 = p0 + 1;
    int t = threadIdx.x;
    int row = t >> 2, c0 = (t & 3) * 32;
    float2 a = Ml[p0 * 64 + row];
    float2 c = Ml[p1 * 64 + row];
    float M = fmaxf(a.x, c.x);
    float w1 = exp2f(a.x - M), w2 = exp2f(c.x - M);
    float inv = 1.0f / (w1 * a.y + w2 * c.y);
    const u16* O1 = Opart + p0 * 8192 + row * 128 + c0;
    const u16* O2 = Opart + p1 * 8192 + row * 128 + c0;
    int qrow = (16 + s16) * 64 + row;
    u16* Yp = Y + ((size_t)(b * T_) + qrow) * 2048 + h * HD_ + c0;
#pragma unroll
    for (int v = 0; v < 4; ++v) {
        u16x8 v1 = *(const u16x8*)(O1 + v * 8);
        u16x8 v2 = *(const u16x8*)(O2 + v * 8);
        u16x8 o;
#pragma unroll
        for (int i = 0; i < 8; ++i)
            o[i] = f2bf((w1 * bf2f(v1[i]) + w2 * bf2f(v2[i])) * inv);
        *(u16x8*)(Yp + v * 8) = o;
    }
}

extern "C" void kernel_launch(void* const* d_in, const int* in_sizes, int n_in,
                              void* d_out, int out_size, void* d_ws, size_t ws_size,
                              hipStream_t stream) {
    const float* x    = (const float*)d_in[0];
    const float* cosT = (const float*)d_in[1];
    const float* sinT = (const float*)d_in[2];
    const float* wq   = (const float*)d_in[3];
    const float* wk   = (const float*)d_in[4];
    const float* wv   = (const float*)d_in[5];
    const float* wo   = (const float*)d_in[6];
    float* out = (float*)d_out;

    char* ws = (char*)d_ws;
    u16*    wqkvT = (u16*)(ws);                      // [3072][2048] bf16
    u16*    woT   = (u16*)(ws + 12582912);           // [2048][2048] bf16
    u16*    xb    = (u16*)(ws + 20971520);           // [4096][2048] bf16
    u16*    qkv   = (u16*)(ws + 37748736);           // [4096][3072] bf16 (ends 62914560)
    u16*    opart = (u16*)(ws + 62914560);           // 1024 x [64][128] bf16 partials (16MB)
    float2* mlbuf = (float2*)(ws + 79691776);        // 1024 x [64] float2 (512KB)
    u16*    qh    = (u16*)(ws + 88080384);           // [2][16][2048][128] bf16
    u16*    kh    = (u16*)(ws + 104857600);          // [2][4][2048][128] bf16
    u16*    vt    = (u16*)(ws + 109051904);          // [2][4][128][2048] bf16 (V^T)
    u16*    y     = xb;                              // reuse (xb dead after GEMM1)

    hipFuncSetAttribute(reinterpret_cast<const void*>(&attn),
                        hipFuncAttributeMaxDynamicSharedMemorySize, 73728);

    prepass<<<18432, 256, 0, stream>>>(wq, wk, wv, wo, (const float4*)x, wqkvT, woT, xb);

    gemm_bf16o<<<dim3(24, 32), 256, 0, stream>>>(xb, wqkvT, qkv, 3072, 2048);

    rope_tv<<<22528, 256, 0, stream>>>(qkv, cosT, sinT, qh, kh, vt);

    attn<<<384, 512, 73728, stream>>>(qh, kh, vt, y, opart, mlbuf);
    combine<<<512, 256, 0, stream>>>(opart, mlbuf, y);

    gemm_bf16<<<dim3(16, 32), 256, 0, stream>>>(y, woT, out, 2048, 2048);
}